// Round 3
// baseline (791.937 us; speedup 1.0000x reference)
//
#include <hip/hip_runtime.h>
#include <hip/hip_bf16.h>
#include <cstdint>
#include <cstddef>

#define NH   16
#define DHD  64
#define DM   1024
#define BSZ  8
#define SEQ  4096
#define NTOK (BSZ*SEQ)      // 32768 tokens
#define NQKV (3*NH*DHD)     // 3072

typedef __attribute__((ext_vector_type(8))) __bf16 bf16x8;
typedef __attribute__((ext_vector_type(4))) float  floatx4;
typedef __attribute__((ext_vector_type(4))) _Float16 f16x4;

// ---- helpers ----
static __device__ __forceinline__ unsigned short f2bf(float f) {
    unsigned int u = __float_as_uint(f);
    u += 0x7fffu + ((u >> 16) & 1u);   // RNE
    return (unsigned short)(u >> 16);
}
static __device__ __forceinline__ float bf2f(unsigned int us) {
    return __uint_as_float(us << 16);
}
static __device__ __forceinline__ unsigned short f2h(float f) {
    _Float16 h = (_Float16)f;
    return __builtin_bit_cast(unsigned short, h);
}
static __device__ __forceinline__ void load_lds16(const void* g, void* l) {
    __builtin_amdgcn_global_load_lds((__attribute__((address_space(1))) void*)g,
                                     (__attribute__((address_space(3))) void*)l,
                                     16, 0, 0);
}

// ---- cast fp32 -> bf16 (vectorized, exact multiple of 4) ----
__global__ __launch_bounds__(256) void k_cast_bf16(const float* __restrict__ in,
                                                   unsigned short* __restrict__ out, int n4) {
    int i = blockIdx.x * 256 + threadIdx.x;
    if (i >= n4) return;
    float4 v = ((const float4*)in)[i];
    ushort4 o;
    o.x = f2bf(v.x); o.y = f2bf(v.y); o.z = f2bf(v.z); o.w = f2bf(v.w);
    ((ushort4*)out)[i] = o;
}

// ---- transpose + cast: in fp32 [R][C] -> out bf16 [C][R] ----
template<int R, int C>
__global__ __launch_bounds__(256) void k_transpose_cast(const float* __restrict__ in,
                                                        unsigned short* __restrict__ out) {
    __shared__ float tile[32][33];
    int tx = threadIdx.x, ty = threadIdx.y;    // (32, 8)
    int col = blockIdx.x * 32 + tx;
#pragma unroll
    for (int k = 0; k < 4; k++) {
        int row = blockIdx.y * 32 + ty + k * 8;
        tile[ty + k * 8][tx] = in[(size_t)row * C + col];
    }
    __syncthreads();
#pragma unroll
    for (int k = 0; k < 4; k++) {
        int ocol = blockIdx.x * 32 + ty + k * 8;   // original col -> out row
        int orow = blockIdx.y * 32 + tx;           // original row -> out col
        out[(size_t)ocol * R + orow] = f2bf(tile[tx][ty + k * 8]);
    }
}

// ---- positional encoding table fp32 [4096][64] ----
__global__ __launch_bounds__(256) void k_pe(float* __restrict__ pe) {
    int t = blockIdx.x * 256 + threadIdx.x;   // 4096*32
    int l = t >> 5, i = t & 31;
    float dv = expf(-0.14391156831212787f * (float)(2 * i));
    float ang = (float)l * dv;
    pe[l * 64 + 2 * i]     = sinf(ang);
    pe[l * 64 + 2 * i + 1] = cosf(ang);
}

// ---- m97-style bf16 GEMM: C[M][N] = A[M][1024] @ BT[N][1024]^T + bias ----
// EPI==1: qkv epilogue (q *= 0.125, k += pe, bf16 store via LDS transpose -> coalesced)
// EPI==0: fp32 direct store (64B segments, already coalesced)
template<int N, int EPI>
__global__ __launch_bounds__(256) void k_gemm(const unsigned short* __restrict__ A,
                                              const unsigned short* __restrict__ BT,
                                              const float* __restrict__ bias,
                                              const float* __restrict__ pe,
                                              void* __restrict__ Cout) {
    constexpr int K = 1024;
    // k-loop: As[128][32] + Bs[128][32] bf16 (8192 shorts); epilogue: T[64][136] (8704 shorts)
    __shared__ __align__(16) short lds[8704];
    short* As = lds;
    short* Bs = lds + 4096;

    int tid  = threadIdx.x;
    int lane = tid & 63;
    int wid  = tid >> 6;
    int m0 = blockIdx.y * 128;
    int n0 = blockIdx.x * 128;
    int wr = wid >> 1, wc = wid & 1;
    int l15 = lane & 15;
    int quad = lane >> 4;
    int kq  = quad * 8;

    floatx4 acc[4][4];
#pragma unroll
    for (int i = 0; i < 4; i++)
#pragma unroll
        for (int j = 0; j < 4; j++) acc[i][j] = (floatx4){0.f, 0.f, 0.f, 0.f};

    int ci0 = wid * 128 + lane;
    int ci1 = ci0 + 64;
    const unsigned short* pa0 = A  + (size_t)(m0 + (ci0 >> 2)) * K + (ci0 & 3) * 8;
    const unsigned short* pa1 = A  + (size_t)(m0 + (ci1 >> 2)) * K + (ci1 & 3) * 8;
    const unsigned short* pb0 = BT + (size_t)(n0 + (ci0 >> 2)) * K + (ci0 & 3) * 8;
    const unsigned short* pb1 = BT + (size_t)(n0 + (ci1 >> 2)) * K + (ci1 & 3) * 8;
    short* la0 = As + ci0 * 8;
    short* la1 = As + ci1 * 8;
    short* lb0 = Bs + ci0 * 8;
    short* lb1 = Bs + ci1 * 8;

    for (int kb = 0; kb < K; kb += 32) {
        __syncthreads();
        load_lds16(pa0 + kb, la0);
        load_lds16(pa1 + kb, la1);
        load_lds16(pb0 + kb, lb0);
        load_lds16(pb1 + kb, lb1);
        __syncthreads();

        bf16x8 aF[4], bF[4];
#pragma unroll
        for (int i = 0; i < 4; i++)
            aF[i] = *(const bf16x8*)&As[(wr * 64 + i * 16 + l15) * 32 + kq];
#pragma unroll
        for (int j = 0; j < 4; j++)
            bF[j] = *(const bf16x8*)&Bs[(wc * 64 + j * 16 + l15) * 32 + kq];
#pragma unroll
        for (int i = 0; i < 4; i++)
#pragma unroll
            for (int j = 0; j < 4; j++)
                acc[i][j] = __builtin_amdgcn_mfma_f32_16x16x32_bf16(aF[i], bF[j], acc[i][j], 0, 0, 0);
    }

    if (EPI == 1) {
        // LDS-transpose epilogue: 2 passes of 64 rows x 128 cols bf16.
        // Full-column XOR swizzle c' = c ^ (row_quad*8): stays in 0..127 (bits 3..4),
        // matches the read-side unswizzle exactly.
        short* T = lds;   // 64 x 136
        __syncthreads();
#pragma unroll
        for (int p = 0; p < 2; p++) {
            if (wr == p) {
#pragma unroll
                for (int j = 0; j < 4; j++) {
                    int col = n0 + wc * 64 + j * 16 + l15;
                    float bv = bias[col];
                    int h = col / 192, rc = col - h * 192;
                    int csw = (wc * 64 + j * 16 + l15) ^ (quad << 3);
#pragma unroll
                    for (int i = 0; i < 4; i++) {
#pragma unroll
                        for (int r = 0; r < 4; r++) {
                            int rl = i * 16 + quad * 4 + r;
                            int row = m0 + p * 64 + rl;
                            float v = acc[i][j][r] + bv;
                            if (rc < 64)       v *= 0.125f;                                  // q / sqrt(64)
                            else if (rc < 128) v += pe[(row & (SEQ - 1)) * 64 + (rc - 64)];  // k + pos_enc
                            T[rl * 136 + csw] = (short)f2bf(v);
                        }
                    }
                }
            }
            __syncthreads();
            {
                int rl = tid >> 2, coff = (tid & 3) * 32;
                int sw = ((rl >> 2) & 3) * 8;
                unsigned short* dst = (unsigned short*)Cout + (size_t)(m0 + p * 64 + rl) * N + n0 + coff;
#pragma unroll
                for (int k = 0; k < 4; k++) {
                    uint4 u = *(const uint4*)&T[rl * 136 + ((coff + k * 8) ^ sw)];
                    *(uint4*)(dst + k * 8) = u;
                }
            }
            __syncthreads();
        }
    } else {
        int rbase = quad * 4;
#pragma unroll
        for (int j = 0; j < 4; j++) {
            int col = n0 + wc * 64 + j * 16 + l15;
            float bv = bias[col];
#pragma unroll
            for (int i = 0; i < 4; i++) {
#pragma unroll
                for (int r = 0; r < 4; r++) {
                    int row = m0 + wr * 64 + i * 16 + rbase + r;
                    ((float*)Cout)[(size_t)row * N + col] = acc[i][j][r] + bv;
                }
            }
        }
    }
}

// ---- per-token across-heads attention, MFMA version: 1 wave per token ----
// qkv row: head h -> [q(64) | k(64) | v(64)] at col h*192; q pre-scaled, k has pe.
// S = Q.K^T via 2x mfma 16x16x32 bf16 (frags straight from global);
// softmax via 16-lane shfl butterflies; PV via 4x mfma 16x16x16 f16 (K=16 exact).
__global__ __launch_bounds__(256) void k_attn(const unsigned short* __restrict__ qkv,
                                              unsigned short* __restrict__ aout) {
    // per-wave: VT f16 [64][20] (1280) | PL f16 [16][20] (320) | OL bf16 [16][72] (1152)
    __shared__ __align__(16) unsigned short lds[4][2752];
    int tid = threadIdx.x, wid = tid >> 6, lane = tid & 63;
    unsigned short* VT = lds[wid];
    unsigned short* PL = VT + 1280;
    unsigned short* OL = PL + 320;
    int t = blockIdx.x * 4 + wid;
    int l15 = lane & 15, q = lane >> 4;

    const unsigned short* rowp = qkv + (size_t)t * NQKV + l15 * 192 + q * 8;

    // fragment loads straight from global (16B/lane; each inst covers full 64B lines)
    bf16x8 aQ0 = *(const bf16x8*)(rowp);          // Q[h=l15][d = q*8 + 0..7]
    bf16x8 bK0 = *(const bf16x8*)(rowp + 64);     // K[g=l15][d = q*8 + 0..7]
    bf16x8 aQ1 = *(const bf16x8*)(rowp + 32);     // d + 32
    bf16x8 bK1 = *(const bf16x8*)(rowp + 96);
    uint4  v0  = *(const uint4*)(rowp + 128);     // V[g=l15][q*8 + 0..7]
    uint4  v1  = *(const uint4*)(rowp + 160);     // V[g=l15][q*8 + 32..39]

    floatx4 S = {0.f, 0.f, 0.f, 0.f};
    S = __builtin_amdgcn_mfma_f32_16x16x32_bf16(aQ0, bK0, S, 0, 0, 0);
    S = __builtin_amdgcn_mfma_f32_16x16x32_bf16(aQ1, bK1, S, 0, 0, 0);
    // S C-layout: lane holds S[h = q*4+r][g = l15], r = 0..3

    // stage V^T as f16 (exact conversion from bf16): VT[d][g]
    {
        unsigned int w0[4] = {v0.x, v0.y, v0.z, v0.w};
        unsigned int w1[4] = {v1.x, v1.y, v1.z, v1.w};
#pragma unroll
        for (int i = 0; i < 4; i++) {
            int d = q * 8 + 2 * i;
            VT[(d)      * 20 + l15] = f2h(bf2f(w0[i] & 0xffff));
            VT[(d + 1)  * 20 + l15] = f2h(bf2f(w0[i] >> 16));
            VT[(d + 32) * 20 + l15] = f2h(bf2f(w1[i] & 0xffff));
            VT[(d + 33) * 20 + l15] = f2h(bf2f(w1[i] >> 16));
        }
    }

    // softmax over g: reduce across the 16 lanes of each quad, per reg (= per row h)
    float e0, e1, e2, e3, i0, i1, i2, i3;
    {
        float m0 = S[0], m1 = S[1], m2 = S[2], m3 = S[3];
#pragma unroll
        for (int d = 1; d < 16; d <<= 1) {
            m0 = fmaxf(m0, __shfl_xor(m0, d));
            m1 = fmaxf(m1, __shfl_xor(m1, d));
            m2 = fmaxf(m2, __shfl_xor(m2, d));
            m3 = fmaxf(m3, __shfl_xor(m3, d));
        }
        e0 = __expf(S[0] - m0); e1 = __expf(S[1] - m1);
        e2 = __expf(S[2] - m2); e3 = __expf(S[3] - m3);
        float s0 = e0, s1 = e1, s2 = e2, s3 = e3;
#pragma unroll
        for (int d = 1; d < 16; d <<= 1) {
            s0 += __shfl_xor(s0, d); s1 += __shfl_xor(s1, d);
            s2 += __shfl_xor(s2, d); s3 += __shfl_xor(s3, d);
        }
        i0 = 1.f / s0; i1 = 1.f / s1; i2 = 1.f / s2; i3 = 1.f / s3;
    }
    // write unnormalized P (f16); normalization folded into O epilogue
    PL[(q * 4 + 0) * 20 + l15] = f2h(e0);
    PL[(q * 4 + 1) * 20 + l15] = f2h(e1);
    PL[(q * 4 + 2) * 20 + l15] = f2h(e2);
    PL[(q * 4 + 3) * 20 + l15] = f2h(e3);

    // PV: O[h][d], K = 16 heads exactly -> mfma 16x16x16 f16, 4 d-chunks
    f16x4 aP = *(const f16x4*)&PL[l15 * 20 + q * 4];   // P[m=l15][k=q*4..+4]
    floatx4 O[4];
#pragma unroll
    for (int c = 0; c < 4; c++) {
        f16x4 bV = *(const f16x4*)&VT[(c * 16 + l15) * 20 + q * 4];  // V[k=q*4+j][n=l15]
        O[c] = __builtin_amdgcn_mfma_f32_16x16x16f16(aP, bV, (floatx4){0.f, 0.f, 0.f, 0.f}, 0, 0, 0);
    }

    // O epilogue: divide rows by softmax sum (lane owns same rows as S), transpose via LDS
    float inv[4] = {i0, i1, i2, i3};
#pragma unroll
    for (int c = 0; c < 4; c++)
#pragma unroll
        for (int r = 0; r < 4; r++)
            OL[(q * 4 + r) * 72 + c * 16 + l15] = f2bf(O[c][r] * inv[r]);

    // coalesced store: wave writes the full 2KB aout row
    int h2 = lane >> 2, a = lane & 3;
    uint4 o0 = *(const uint4*)&OL[h2 * 72 + a * 16];
    uint4 o1 = *(const uint4*)&OL[h2 * 72 + a * 16 + 8];
    uint4* dst = (uint4*)&aout[(size_t)t * DM + lane * 16];
    dst[0] = o0;
    dst[1] = o1;
}

extern "C" void kernel_launch(void* const* d_in, const int* in_sizes, int n_in,
                              void* d_out, int out_size, void* d_ws, size_t ws_size,
                              hipStream_t stream) {
    const float* x     = (const float*)d_in[0];
    const float* w_qkv = (const float*)d_in[1];
    const float* b_qkv = (const float*)d_in[2];
    const float* w_out = (const float*)d_in[3];
    const float* b_out = (const float*)d_in[4];
    float* out = (float*)d_out;

    // ws layout: pe fp32[4096][64] | wqkvT bf16[3072][1024] | woutT bf16[1024][1024]
    //            | xbf bf16[32768][1024] (reused as attn out) | qkv bf16[32768][3072]
    char* ws = (char*)d_ws;
    float*          pe    = (float*)ws;
    unsigned short* wqkvT = (unsigned short*)(ws + (1u << 20));
    unsigned short* woutT = (unsigned short*)(ws + (1u << 20) + 6291456u);
    unsigned short* xbf   = (unsigned short*)(ws + (1u << 20) + 6291456u + 2097152u);
    unsigned short* qkv   = (unsigned short*)(ws + (1u << 20) + 6291456u + 2097152u + 67108864u);
    unsigned short* aout  = xbf;  // x_bf16 dead after GEMM1; reuse for attention output

    k_cast_bf16<<<(NTOK * DM / 4 + 255) / 256, 256, 0, stream>>>(x, xbf, NTOK * DM / 4);
    k_transpose_cast<1024, 3072><<<dim3(96, 32), dim3(32, 8), 0, stream>>>(w_qkv, wqkvT);
    k_transpose_cast<1024, 1024><<<dim3(32, 32), dim3(32, 8), 0, stream>>>(w_out, woutT);
    k_pe<<<512, 256, 0, stream>>>(pe);

    k_gemm<NQKV, 1><<<dim3(NQKV / 128, NTOK / 128), 256, 0, stream>>>(xbf, wqkvT, b_qkv, pe, qkv);
    k_attn<<<NTOK / 4, 256, 0, stream>>>(qkv, aout);
    k_gemm<DM, 0><<<dim3(DM / 128, NTOK / 128), 256, 0, stream>>>(aout, woutT, b_out, nullptr, out);
}

// Round 5
// 782.933 us; speedup vs baseline: 1.0115x; 1.0115x over previous
//
#include <hip/hip_runtime.h>
#include <hip/hip_bf16.h>
#include <cstdint>
#include <cstddef>

#define NH   16
#define DHD  64
#define DM   1024
#define BSZ  8
#define SEQ  4096
#define NTOK (BSZ*SEQ)      // 32768 tokens
#define NQKV (3*NH*DHD)     // 3072

typedef __attribute__((ext_vector_type(8))) __bf16 bf16x8;
typedef __attribute__((ext_vector_type(4))) float  floatx4;
typedef __attribute__((ext_vector_type(4))) _Float16 f16x4;

// ---- helpers ----
static __device__ __forceinline__ unsigned short f2bf(float f) {
    unsigned int u = __float_as_uint(f);
    u += 0x7fffu + ((u >> 16) & 1u);   // RNE
    return (unsigned short)(u >> 16);
}
static __device__ __forceinline__ float bf2f(unsigned int us) {
    return __uint_as_float(us << 16);
}
static __device__ __forceinline__ unsigned short f2h(float f) {
    _Float16 h = (_Float16)f;
    return __builtin_bit_cast(unsigned short, h);
}
static __device__ __forceinline__ void load_lds16(const void* g, void* l) {
    // NOTE: the imm offset arg applies to BOTH global and LDS addresses
    // (R4 NaN root cause) — always pass 0 and put offsets in the pointers.
    __builtin_amdgcn_global_load_lds((__attribute__((address_space(1))) void*)g,
                                     (__attribute__((address_space(3))) void*)l,
                                     16, 0, 0);
}

// ---- cast fp32 -> bf16 (vectorized, exact multiple of 4) ----
__global__ __launch_bounds__(256) void k_cast_bf16(const float* __restrict__ in,
                                                   unsigned short* __restrict__ out, int n4) {
    int i = blockIdx.x * 256 + threadIdx.x;
    if (i >= n4) return;
    float4 v = ((const float4*)in)[i];
    ushort4 o;
    o.x = f2bf(v.x); o.y = f2bf(v.y); o.z = f2bf(v.z); o.w = f2bf(v.w);
    ((ushort4*)out)[i] = o;
}

// ---- transpose + cast: in fp32 [R][C] -> out bf16 [C][R] ----
template<int R, int C>
__global__ __launch_bounds__(256) void k_transpose_cast(const float* __restrict__ in,
                                                        unsigned short* __restrict__ out) {
    __shared__ float tile[32][33];
    int tx = threadIdx.x, ty = threadIdx.y;    // (32, 8)
    int col = blockIdx.x * 32 + tx;
#pragma unroll
    for (int k = 0; k < 4; k++) {
        int row = blockIdx.y * 32 + ty + k * 8;
        tile[ty + k * 8][tx] = in[(size_t)row * C + col];
    }
    __syncthreads();
#pragma unroll
    for (int k = 0; k < 4; k++) {
        int ocol = blockIdx.x * 32 + ty + k * 8;   // original col -> out row
        int orow = blockIdx.y * 32 + tx;           // original row -> out col
        out[(size_t)ocol * R + orow] = f2bf(tile[tx][ty + k * 8]);
    }
}

// ---- positional encoding table fp32 [4096][64] ----
__global__ __launch_bounds__(256) void k_pe(float* __restrict__ pe) {
    int t = blockIdx.x * 256 + threadIdx.x;   // 4096*32
    int l = t >> 5, i = t & 31;
    float dv = expf(-0.14391156831212787f * (float)(2 * i));
    float ang = (float)l * dv;
    pe[l * 64 + 2 * i]     = sinf(ang);
    pe[l * 64 + 2 * i + 1] = cosf(ang);
}

// ---- bf16 GEMM, BK=64 double-stage: C[M][N] = A[M][1024] @ BT[N][1024]^T + bias ----
// EPI==1: qkv epilogue (q *= 0.125, k += pe, bf16 store via parallel LDS transpose)
// EPI==0: fp32 direct store
template<int N, int EPI>
__global__ __launch_bounds__(256) void k_gemm(const unsigned short* __restrict__ A,
                                              const unsigned short* __restrict__ BT,
                                              const float* __restrict__ bias,
                                              const float* __restrict__ pe,
                                              void* __restrict__ Cout) {
    constexpr int K = 1024;
    // k-loop: As0|Bs0|As1|Bs1 each [128][32] bf16 (16384 shorts, 32KB)
    // epilogue (EPI==1): T[128][136] (17408 shorts, 34.8KB) — union
    __shared__ __align__(16) short lds[17408];
    short* As0 = lds;
    short* Bs0 = lds + 4096;
    short* As1 = lds + 8192;
    short* Bs1 = lds + 12288;

    int tid  = threadIdx.x;
    int lane = tid & 63;
    int wid  = tid >> 6;           // 4 waves
    int m0 = blockIdx.y * 128;
    int n0 = blockIdx.x * 128;
    int wr = wid >> 1, wc = wid & 1;
    int l15 = lane & 15;
    int quad = lane >> 4;
    int kq  = quad * 8;

    floatx4 acc[4][4];
#pragma unroll
    for (int i = 0; i < 4; i++)
#pragma unroll
        for (int j = 0; j < 4; j++) acc[i][j] = (floatx4){0.f, 0.f, 0.f, 0.f};

    // staging: 512 16B-chunks per [128][32] buffer; chunk ci -> row ci>>2, col (ci&3)*8
    int ci0 = wid * 128 + lane;
    int ci1 = ci0 + 64;
    const unsigned short* pa0 = A  + (size_t)(m0 + (ci0 >> 2)) * K + (ci0 & 3) * 8;
    const unsigned short* pa1 = A  + (size_t)(m0 + (ci1 >> 2)) * K + (ci1 & 3) * 8;
    const unsigned short* pb0 = BT + (size_t)(n0 + (ci0 >> 2)) * K + (ci0 & 3) * 8;
    const unsigned short* pb1 = BT + (size_t)(n0 + (ci1 >> 2)) * K + (ci1 & 3) * 8;
    short* la0 = As0 + ci0 * 8;
    short* la1 = As0 + ci1 * 8;
    short* lb0 = Bs0 + ci0 * 8;
    short* lb1 = Bs0 + ci1 * 8;

    auto compute32 = [&](const short* Asb, const short* Bsb) {
        bf16x8 aF[4], bF[4];
#pragma unroll
        for (int i = 0; i < 4; i++)
            aF[i] = *(const bf16x8*)&Asb[(wr * 64 + i * 16 + l15) * 32 + kq];
#pragma unroll
        for (int j = 0; j < 4; j++)
            bF[j] = *(const bf16x8*)&Bsb[(wc * 64 + j * 16 + l15) * 32 + kq];
#pragma unroll
        for (int i = 0; i < 4; i++)
#pragma unroll
            for (int j = 0; j < 4; j++)
                acc[i][j] = __builtin_amdgcn_mfma_f32_16x16x32_bf16(aF[i], bF[j], acc[i][j], 0, 0, 0);
    };

    for (int kb = 0; kb < K; kb += 64) {
        __syncthreads();
        // stage 0: columns kb .. kb+31
        load_lds16(pa0 + kb, la0);
        load_lds16(pa1 + kb, la1);
        load_lds16(pb0 + kb, lb0);
        load_lds16(pb1 + kb, lb1);
        // stage 1: columns kb+32 .. kb+63 (explicit pointers, offset arg stays 0)
        load_lds16(pa0 + kb + 32, la0 + 8192);
        load_lds16(pa1 + kb + 32, la1 + 8192);
        load_lds16(pb0 + kb + 32, lb0 + 8192);
        load_lds16(pb1 + kb + 32, lb1 + 8192);
        __syncthreads();
        compute32(As0, Bs0);
        compute32(As1, Bs1);
    }

    if (EPI == 1) {
        // Parallel LDS-transpose epilogue: all 4 waves write their 64x64 sub-tiles,
        // one barrier, then 256 threads stream out 128 rows x 256B coalesced.
        // Swizzle c' = c ^ (row_quad*8): bits 3..4 only, matches read-side unswizzle.
        short* T = lds;   // [128][136]
        __syncthreads();
#pragma unroll
        for (int j = 0; j < 4; j++) {
            int col = n0 + wc * 64 + j * 16 + l15;
            float bv = bias[col];
            int h = col / 192, rc = col - h * 192;
            int csw = (wc * 64 + j * 16 + l15) ^ (quad << 3);
#pragma unroll
            for (int i = 0; i < 4; i++) {
#pragma unroll
                for (int r = 0; r < 4; r++) {
                    int rl = wr * 64 + i * 16 + quad * 4 + r;
                    int row = m0 + rl;
                    float v = acc[i][j][r] + bv;
                    if (rc < 64)       v *= 0.125f;                                  // q / sqrt(64)
                    else if (rc < 128) v += pe[(row & (SEQ - 1)) * 64 + (rc - 64)];  // k + pos_enc
                    T[rl * 136 + csw] = (short)f2bf(v);
                }
            }
        }
        __syncthreads();
        {
            int row = tid >> 1, coff = (tid & 1) * 64;
            int sw = ((row >> 2) & 3) * 8;
            unsigned short* dst = (unsigned short*)Cout + (size_t)(m0 + row) * N + n0 + coff;
#pragma unroll
            for (int k = 0; k < 8; k++) {
                uint4 u = *(const uint4*)&T[row * 136 + ((coff + k * 8) ^ sw)];
                *(uint4*)(dst + k * 8) = u;
            }
        }
    } else {
        int rbase = quad * 4;
#pragma unroll
        for (int j = 0; j < 4; j++) {
            int col = n0 + wc * 64 + j * 16 + l15;
            float bv = bias[col];
#pragma unroll
            for (int i = 0; i < 4; i++) {
#pragma unroll
                for (int r = 0; r < 4; r++) {
                    int row = m0 + wr * 64 + i * 16 + rbase + r;
                    ((float*)Cout)[(size_t)row * N + col] = acc[i][j][r] + bv;
                }
            }
        }
    }
}

// ---- per-token across-heads attention, MFMA version: 1 wave per token ----
// qkv row: head h -> [q(64) | k(64) | v(64)] at col h*192; q pre-scaled, k has pe.
__global__ __launch_bounds__(256) void k_attn(const unsigned short* __restrict__ qkv,
                                              unsigned short* __restrict__ aout) {
    // per-wave: VT f16 [64][20] (1280) | PL f16 [16][20] (320) | OL bf16 [16][72] (1152)
    __shared__ __align__(16) unsigned short lds[4][2752];
    int tid = threadIdx.x, wid = tid >> 6, lane = tid & 63;
    unsigned short* VT = lds[wid];
    unsigned short* PL = VT + 1280;
    unsigned short* OL = PL + 320;
    int t = blockIdx.x * 4 + wid;
    int l15 = lane & 15, q = lane >> 4;

    const unsigned short* rowp = qkv + (size_t)t * NQKV + l15 * 192 + q * 8;

    bf16x8 aQ0 = *(const bf16x8*)(rowp);          // Q[h=l15][d = q*8 + 0..7]
    bf16x8 bK0 = *(const bf16x8*)(rowp + 64);     // K[g=l15][d = q*8 + 0..7]
    bf16x8 aQ1 = *(const bf16x8*)(rowp + 32);     // d + 32
    bf16x8 bK1 = *(const bf16x8*)(rowp + 96);
    uint4  v0  = *(const uint4*)(rowp + 128);     // V[g=l15][q*8 + 0..7]
    uint4  v1  = *(const uint4*)(rowp + 160);     // V[g=l15][q*8 + 32..39]

    floatx4 S = {0.f, 0.f, 0.f, 0.f};
    S = __builtin_amdgcn_mfma_f32_16x16x32_bf16(aQ0, bK0, S, 0, 0, 0);
    S = __builtin_amdgcn_mfma_f32_16x16x32_bf16(aQ1, bK1, S, 0, 0, 0);
    // S C-layout: lane holds S[h = q*4+r][g = l15], r = 0..3

    {
        unsigned int w0[4] = {v0.x, v0.y, v0.z, v0.w};
        unsigned int w1[4] = {v1.x, v1.y, v1.z, v1.w};
#pragma unroll
        for (int i = 0; i < 4; i++) {
            int d = q * 8 + 2 * i;
            VT[(d)      * 20 + l15] = f2h(bf2f(w0[i] & 0xffff));
            VT[(d + 1)  * 20 + l15] = f2h(bf2f(w0[i] >> 16));
            VT[(d + 32) * 20 + l15] = f2h(bf2f(w1[i] & 0xffff));
            VT[(d + 33) * 20 + l15] = f2h(bf2f(w1[i] >> 16));
        }
    }

    float e0, e1, e2, e3, i0, i1, i2, i3;
    {
        float m0 = S[0], m1 = S[1], m2 = S[2], m3 = S[3];
#pragma unroll
        for (int d = 1; d < 16; d <<= 1) {
            m0 = fmaxf(m0, __shfl_xor(m0, d));
            m1 = fmaxf(m1, __shfl_xor(m1, d));
            m2 = fmaxf(m2, __shfl_xor(m2, d));
            m3 = fmaxf(m3, __shfl_xor(m3, d));
        }
        e0 = __expf(S[0] - m0); e1 = __expf(S[1] - m1);
        e2 = __expf(S[2] - m2); e3 = __expf(S[3] - m3);
        float s0 = e0, s1 = e1, s2 = e2, s3 = e3;
#pragma unroll
        for (int d = 1; d < 16; d <<= 1) {
            s0 += __shfl_xor(s0, d); s1 += __shfl_xor(s1, d);
            s2 += __shfl_xor(s2, d); s3 += __shfl_xor(s3, d);
        }
        i0 = 1.f / s0; i1 = 1.f / s1; i2 = 1.f / s2; i3 = 1.f / s3;
    }
    PL[(q * 4 + 0) * 20 + l15] = f2h(e0);
    PL[(q * 4 + 1) * 20 + l15] = f2h(e1);
    PL[(q * 4 + 2) * 20 + l15] = f2h(e2);
    PL[(q * 4 + 3) * 20 + l15] = f2h(e3);

    f16x4 aP = *(const f16x4*)&PL[l15 * 20 + q * 4];   // P[m=l15][k=q*4..+4]
    floatx4 O[4];
#pragma unroll
    for (int c = 0; c < 4; c++) {
        f16x4 bV = *(const f16x4*)&VT[(c * 16 + l15) * 20 + q * 4];  // V[k=q*4+j][n=l15]
        O[c] = __builtin_amdgcn_mfma_f32_16x16x16f16(aP, bV, (floatx4){0.f, 0.f, 0.f, 0.f}, 0, 0, 0);
    }

    float inv[4] = {i0, i1, i2, i3};
#pragma unroll
    for (int c = 0; c < 4; c++)
#pragma unroll
        for (int r = 0; r < 4; r++)
            OL[(q * 4 + r) * 72 + c * 16 + l15] = f2bf(O[c][r] * inv[r]);

    int h2 = lane >> 2, a = lane & 3;
    uint4 o0 = *(const uint4*)&OL[h2 * 72 + a * 16];
    uint4 o1 = *(const uint4*)&OL[h2 * 72 + a * 16 + 8];
    uint4* dst = (uint4*)&aout[(size_t)t * DM + lane * 16];
    dst[0] = o0;
    dst[1] = o1;
}

extern "C" void kernel_launch(void* const* d_in, const int* in_sizes, int n_in,
                              void* d_out, int out_size, void* d_ws, size_t ws_size,
                              hipStream_t stream) {
    const float* x     = (const float*)d_in[0];
    const float* w_qkv = (const float*)d_in[1];
    const float* b_qkv = (const float*)d_in[2];
    const float* w_out = (const float*)d_in[3];
    const float* b_out = (const float*)d_in[4];
    float* out = (float*)d_out;

    // ws layout: pe fp32[4096][64] | wqkvT bf16[3072][1024] | woutT bf16[1024][1024]
    //            | xbf bf16[32768][1024] (reused as attn out) | qkv bf16[32768][3072]
    char* ws = (char*)d_ws;
    float*          pe    = (float*)ws;
    unsigned short* wqkvT = (unsigned short*)(ws + (1u << 20));
    unsigned short* woutT = (unsigned short*)(ws + (1u << 20) + 6291456u);
    unsigned short* xbf   = (unsigned short*)(ws + (1u << 20) + 6291456u + 2097152u);
    unsigned short* qkv   = (unsigned short*)(ws + (1u << 20) + 6291456u + 2097152u + 67108864u);
    unsigned short* aout  = xbf;  // x_bf16 dead after GEMM1; reuse for attention output

    k_cast_bf16<<<(NTOK * DM / 4 + 255) / 256, 256, 0, stream>>>(x, xbf, NTOK * DM / 4);
    k_transpose_cast<1024, 3072><<<dim3(96, 32), dim3(32, 8), 0, stream>>>(w_qkv, wqkvT);
    k_transpose_cast<1024, 1024><<<dim3(32, 32), dim3(32, 8), 0, stream>>>(w_out, woutT);
    k_pe<<<512, 256, 0, stream>>>(pe);

    k_gemm<NQKV, 1><<<dim3(NQKV / 128, NTOK / 128), 256, 0, stream>>>(xbf, wqkvT, b_qkv, pe, qkv);
    k_attn<<<NTOK / 4, 256, 0, stream>>>(qkv, aout);
    k_gemm<DM, 0><<<dim3(DM / 128, NTOK / 128), 256, 0, stream>>>(aout, woutT, b_out, nullptr, out);
}